// Round 2
// baseline (24798.752 us; speedup 1.0000x reference)
//
#include <hip/hip_runtime.h>

#define HD 300
#define KC 75          // HD/4 k-chunks
#define BD 64
#define VD 100000
#define LD 64
#define NPB 1563       // proj blocks: 1563*64 = 100032 >= VD

__device__ __forceinline__ float sigm(float x) { return 1.0f / (1.0f + expf(-x)); }

// Transposed k-chunked layout: T[kc][b][e] = X[b][4*kc+e], size 75*64*4 floats.
__device__ __forceinline__ int tidx(int k, int b) {
  return (k >> 2) * 256 + b * 4 + (k & 3);
}

// ---------------------------------------------------------------------------
// k_prep: build transposed encoder inputs for ALL 64 steps up front.
// xall[t][kc][b][e] = emb[input[t][b]][4kc+e]   (no relu: encoder x is raw emb)
// ---------------------------------------------------------------------------
__global__ __launch_bounds__(320) void k_prep(
    const int* __restrict__ input, const float* __restrict__ emb,
    float* __restrict__ xall)
{
  const int t = blockIdx.x, b = blockIdx.y;
  const int k = threadIdx.x;
  if (k >= HD) return;
  const int id = input[t * BD + b];
  xall[t * (KC * 256) + tidx(k, b)] = emb[(size_t)id * HD + k];
}

// ---------------------------------------------------------------------------
// k_init: zero h (transposed buf) and build decoder step-0 x = relu(emb[0]).
// ---------------------------------------------------------------------------
__global__ __launch_bounds__(320) void k_init(
    float* __restrict__ hT, const float* __restrict__ emb, float* __restrict__ xdec)
{
  const int b = blockIdx.x;
  const int k = threadIdx.x;
  if (k >= HD) return;
  hT[tidx(k, b)] = 0.f;
  xdec[tidx(k, b)] = fmaxf(emb[k], 0.f);
}

// ---------------------------------------------------------------------------
// k_gru: 150 blocks x 384 threads (6 waves). Wave w -> gate g=w>>1, j=w&1,
// output i0 = 2*blk + j; lane = batch b. Weight rows: wave-uniform scalar
// streams. xT/hT: coalesced float4 per lane. float4 partial accs break the
// 300-deep FMA chain. Gates combined via LDS by waves 0,1.
// ---------------------------------------------------------------------------
__global__ __launch_bounds__(384) void k_gru(
    const float* __restrict__ xT, const float* __restrict__ hT_in,
    const float* __restrict__ W_ih, const float* __restrict__ W_hh,
    const float* __restrict__ b_ih, const float* __restrict__ b_hh,
    float* __restrict__ hT_out)
{
  const int w = threadIdx.x >> 6;   // 0..5
  const int b = threadIdx.x & 63;
  const int g = w >> 1;             // 0=r 1=z 2=n
  const int j = w & 1;
  const int i0 = blockIdx.x * 2 + j;

  const float* Wrow = W_ih + (size_t)(g * HD + i0) * HD;
  const float* Urow = W_hh + (size_t)(g * HD + i0) * HD;

  float4 gi4 = make_float4(0.f, 0.f, 0.f, 0.f);
  float4 gh4 = make_float4(0.f, 0.f, 0.f, 0.f);

  for (int kc = 0; kc < KC; kc++) {
    const float4 wv = *(const float4*)(Wrow + kc * 4);        // uniform -> s_load
    const float4 uv = *(const float4*)(Urow + kc * 4);        // uniform -> s_load
    const float4 xv = *(const float4*)(xT + kc * 256 + b * 4);    // coalesced
    const float4 hv = *(const float4*)(hT_in + kc * 256 + b * 4); // coalesced
    gi4.x += wv.x * xv.x; gi4.y += wv.y * xv.y; gi4.z += wv.z * xv.z; gi4.w += wv.w * xv.w;
    gh4.x += uv.x * hv.x; gh4.y += uv.y * hv.y; gh4.z += uv.z * hv.z; gh4.w += uv.w * hv.w;
  }

  const float gi = ((gi4.x + gi4.y) + (gi4.z + gi4.w)) + b_ih[g * HD + i0];
  const float gh = ((gh4.x + gh4.y) + (gh4.z + gh4.w)) + b_hh[g * HD + i0];

  __shared__ float sgi[6][64];
  __shared__ float sgh[6][64];
  sgi[w][b] = gi;
  sgh[w][b] = gh;
  __syncthreads();

  if (w < 2) {                      // j == w here; i0 matches
    const float r = sigm(sgi[j][b] + sgh[j][b]);
    const float z = sigm(sgi[2 + j][b] + sgh[2 + j][b]);
    const float n = tanhf(sgi[4 + j][b] + r * sgh[4 + j][b]);
    const float hp = hT_in[tidx(i0, b)];
    hT_out[tidx(i0, b)] = (1.f - z) * n + z * hp;
  }
}

// ---------------------------------------------------------------------------
// k_proj: 1563 blocks x 64 threads. Thread = 1 vocab column, acc[64] = all
// batch rows (W read exactly once per step). h slices are wave-uniform ->
// scalar loads. Epilogue: per-row wave max + ballot (first-index tie-break),
// winning lane writes packed (value, ~col) u64 key to bb[b][blk].
// ---------------------------------------------------------------------------
__global__ __launch_bounds__(64) void k_proj(
    const float* __restrict__ hT,     // [75][64][4] transposed h
    const float* __restrict__ outW,   // [V][300]
    const float* __restrict__ outb,   // [V]
    unsigned long long* __restrict__ bb)  // [64][NPB]
{
  const int lane = threadIdx.x;
  const int col  = blockIdx.x * 64 + lane;
  const int cw   = (col < VD) ? col : (VD - 1);   // clamp for safe loads
  const bool valid = (col < VD);

  const float* wrow = outW + (size_t)cw * HD;

  float acc[64];
#pragma unroll
  for (int t = 0; t < 64; t++) acc[t] = 0.f;

  for (int kc = 0; kc < KC; kc++) {
    const float4 wv = *(const float4*)(wrow + kc * 4);
    const float* hbase = hT + kc * 256;
#pragma unroll
    for (int b2 = 0; b2 < 64; b2++) {
      const float4 hv = *(const float4*)(hbase + b2 * 4);   // uniform -> s_load
      acc[b2] += wv.x * hv.x + wv.y * hv.y + wv.z * hv.z + wv.w * hv.w;
    }
  }

  const float ob = outb[cw];

#pragma unroll 1
  for (int b2 = 0; b2 < 64; b2++) {
    float me = valid ? (acc[b2] + ob) : -INFINITY;
    float m = me;
#pragma unroll
    for (int off = 32; off >= 1; off >>= 1)
      m = fmaxf(m, __shfl_xor(m, off, 64));
    const unsigned long long mask = __ballot(me == m);
    const int first = __ffsll((long long)mask) - 1;
    if (lane == first) {
      unsigned u = __float_as_uint(m);
      u = (u & 0x80000000u) ? ~u : (u | 0x80000000u);
      const unsigned long long key =
          ((unsigned long long)u << 32) | (unsigned long long)(0xFFFFFFFFu - (unsigned)col);
      bb[(size_t)b2 * NPB + blockIdx.x] = key;
    }
  }
}

// ---------------------------------------------------------------------------
// k_fin: 64 blocks (one per batch row) x 320 threads. Reduce NPB keys ->
// token id; write out[s][b]; build next decoder x (transposed, relu).
// ---------------------------------------------------------------------------
__global__ __launch_bounds__(320) void k_fin(
    const unsigned long long* __restrict__ bb,
    const float* __restrict__ emb,
    float* __restrict__ out_row,     // out + s*B
    float* __restrict__ xdec)        // [75][64][4]
{
  const int b = blockIdx.x;
  const unsigned long long* row = bb + (size_t)b * NPB;

  unsigned long long best = 0ull;
  for (int i = threadIdx.x; i < NPB; i += 320)
    best = max(best, row[i]);

  const int lane = threadIdx.x & 63;
  const int wv = threadIdx.x >> 6;
#pragma unroll
  for (int off = 32; off >= 1; off >>= 1) {
    unsigned long long o;
    int lo = __shfl_xor((int)(unsigned)best, off, 64);
    int hi = __shfl_xor((int)(unsigned)(best >> 32), off, 64);
    o = ((unsigned long long)(unsigned)hi << 32) | (unsigned)lo;
    best = max(best, o);
  }

  __shared__ unsigned long long sm[5];
  __shared__ int sid;
  if (lane == 0) sm[wv] = best;
  __syncthreads();
  if (threadIdx.x == 0) {
    unsigned long long m = sm[0];
#pragma unroll
    for (int i = 1; i < 5; i++) m = max(m, sm[i]);
    const int id = (int)(0xFFFFFFFFu - (unsigned)(m & 0xFFFFFFFFull));
    out_row[b] = (float)id;
    sid = id;
  }
  __syncthreads();

  const int id = sid;
  const int k = threadIdx.x;
  if (k < HD) {
    xdec[tidx(k, b)] = fmaxf(emb[(size_t)id * HD + k], 0.f);
  }
}

// ---------------------------------------------------------------------------
extern "C" void kernel_launch(void* const* d_in, const int* in_sizes, int n_in,
                              void* d_out, int out_size, void* d_ws, size_t ws_size,
                              hipStream_t stream) {
  const int*   input  = (const int*)d_in[0];
  const float* emb    = (const float*)d_in[1];
  const float* eWih   = (const float*)d_in[2];
  const float* eWhh   = (const float*)d_in[3];
  const float* eBih   = (const float*)d_in[4];
  const float* eBhh   = (const float*)d_in[5];
  const float* dWih   = (const float*)d_in[6];
  const float* dWhh   = (const float*)d_in[7];
  const float* dBih   = (const float*)d_in[8];
  const float* dBhh   = (const float*)d_in[9];
  const float* outW   = (const float*)d_in[10];
  const float* outb   = (const float*)d_in[11];
  float* out = (float*)d_out;

  // ws layout: bb (u64, 64*NPB) | hA | hB | xdec | xall (floats)
  unsigned long long* bb = (unsigned long long*)d_ws;
  float* fbase = (float*)((char*)d_ws + (size_t)BD * NPB * 8);
  float* hA   = fbase;                 // 19200 floats
  float* hB   = fbase + 19200;
  float* xdec = fbase + 38400;
  float* xall = fbase + 57600;         // 64 * 19200 floats

  k_prep<<<dim3(LD, BD), 320, 0, stream>>>(input, emb, xall);
  k_init<<<BD, 320, 0, stream>>>(hA, emb, xdec);

  // ---- encoder ----
  for (int t = 0; t < LD; t++) {
    float* hin  = (t & 1) ? hB : hA;
    float* hout = (t & 1) ? hA : hB;
    k_gru<<<150, 384, 0, stream>>>(xall + t * (KC * 256), hin,
                                   eWih, eWhh, eBih, eBhh, hout);
  }
  // t=63 odd: enc_h in hA

  // ---- decoder ----
  for (int s = 0; s < LD; s++) {
    float* hin  = (s & 1) ? hB : hA;
    float* hout = (s & 1) ? hA : hB;
    k_gru<<<150, 384, 0, stream>>>(xdec, hin, dWih, dWhh, dBih, dBhh, hout);
    k_proj<<<NPB, 64, 0, stream>>>(hout, outW, outb, bb);
    k_fin<<<BD, 320, 0, stream>>>(bb, emb, out + s * BD, xdec);
  }
}

// Round 3
// 10885.633 us; speedup vs baseline: 2.2781x; 2.2781x over previous
//
#include <hip/hip_runtime.h>

#define HD 300
#define KC 75          // HD/4 k-chunks
#define BD 64
#define VD 100000
#define LD 64
#define NPB 1024       // proj blocks (= 4 blocks/CU * 256 CUs, all co-resident)

__device__ __forceinline__ float sigm(float x) { return 1.0f / (1.0f + expf(-x)); }

// Transposed k-chunked layout: T[kc][b][e] = X[b][4*kc+e], size 75*64*4 floats.
__device__ __forceinline__ int tidx(int k, int b) {
  return (k >> 2) * 256 + b * 4 + (k & 3);
}

// ---------------------------------------------------------------------------
// k_prep: transposed encoder inputs for all 64 steps.
// xall[t][kc][b][e] = emb[input[t][b]][4kc+e]
// ---------------------------------------------------------------------------
__global__ __launch_bounds__(320) void k_prep(
    const int* __restrict__ input, const float* __restrict__ emb,
    float* __restrict__ xall)
{
  const int t = blockIdx.x, b = blockIdx.y;
  const int k = threadIdx.x;
  if (k >= HD) return;
  const int id = input[t * BD + b];
  xall[t * (KC * 256) + tidx(k, b)] = emb[(size_t)id * HD + k];
}

__global__ __launch_bounds__(320) void k_init(
    float* __restrict__ hT, const float* __restrict__ emb, float* __restrict__ xdec)
{
  const int b = blockIdx.x;
  const int k = threadIdx.x;
  if (k >= HD) return;
  hT[tidx(k, b)] = 0.f;
  xdec[tidx(k, b)] = fmaxf(emb[k], 0.f);
}

// ---------------------------------------------------------------------------
// k_gru: 75 blocks x 384 threads (6 waves). Wave w -> m=w&1 (0: x@W_ih,
// 1: h@W_hh), gate g=w>>1. Each wave computes 4 output rows i=4*blk+r for its
// (matrix, gate): per iter 1 coalesced float4 of x-or-h + 4 uniform W float4
// (s_load) + 16 v_fma. Epilogue combines gates via LDS; waves 0..3 write row r=w.
// ---------------------------------------------------------------------------
__global__ __launch_bounds__(384) void k_gru(
    const float* __restrict__ xT, const float* __restrict__ hT_in,
    const float* __restrict__ W_ih, const float* __restrict__ W_hh,
    const float* __restrict__ b_ih, const float* __restrict__ b_hh,
    float* __restrict__ hT_out)
{
  const int w = __builtin_amdgcn_readfirstlane(threadIdx.x >> 6);  // 0..5
  const int b = threadIdx.x & 63;
  const int m = w & 1;              // 0: input path, 1: hidden path
  const int g = w >> 1;             // 0=r 1=z 2=n
  const int i0 = blockIdx.x * 4;

  const float* src = m ? hT_in : xT;
  const float* M   = m ? W_hh : W_ih;
  const float* row0 = M + (size_t)(g * HD + i0) * HD;

  float4 a0 = {0,0,0,0}, a1 = {0,0,0,0}, a2 = {0,0,0,0}, a3 = {0,0,0,0};

  for (int kc = 0; kc < KC; kc++) {
    const float4 s = *(const float4*)(src + kc * 256 + b * 4);       // coalesced
    const float4 w0 = *(const float4*)(row0 + kc * 4);               // s_load
    const float4 w1 = *(const float4*)(row0 + HD + kc * 4);
    const float4 w2 = *(const float4*)(row0 + 2 * HD + kc * 4);
    const float4 w3 = *(const float4*)(row0 + 3 * HD + kc * 4);
    a0.x += w0.x * s.x; a0.y += w0.y * s.y; a0.z += w0.z * s.z; a0.w += w0.w * s.w;
    a1.x += w1.x * s.x; a1.y += w1.y * s.y; a1.z += w1.z * s.z; a1.w += w1.w * s.w;
    a2.x += w2.x * s.x; a2.y += w2.y * s.y; a2.z += w2.z * s.z; a2.w += w2.w * s.w;
    a3.x += w3.x * s.x; a3.y += w3.y * s.y; a3.z += w3.z * s.z; a3.w += w3.w * s.w;
  }

  const float* bias = m ? b_hh : b_ih;
  __shared__ float sg[2][3][4][64];
  sg[m][g][0][b] = (a0.x + a0.y) + (a0.z + a0.w) + bias[g * HD + i0 + 0];
  sg[m][g][1][b] = (a1.x + a1.y) + (a1.z + a1.w) + bias[g * HD + i0 + 1];
  sg[m][g][2][b] = (a2.x + a2.y) + (a2.z + a2.w) + bias[g * HD + i0 + 2];
  sg[m][g][3][b] = (a3.x + a3.y) + (a3.z + a3.w) + bias[g * HD + i0 + 3];
  __syncthreads();

  if (w < 4) {
    const int r = w;
    const int i = i0 + r;
    const float rr = sigm(sg[0][0][r][b] + sg[1][0][r][b]);
    const float zz = sigm(sg[0][1][r][b] + sg[1][1][r][b]);
    const float nn = tanhf(sg[0][2][r][b] + rr * sg[1][2][r][b]);
    const float hp = hT_in[tidx(i, b)];
    hT_out[tidx(i, b)] = (1.f - zz) * nn + zz * hp;
  }
}

// ---------------------------------------------------------------------------
// k_projmax: lane = batch row. 1024 blocks x 256 threads (4 waves = 4
// K-quarters of h in VGPRs: 76/76/76/72 floats per lane). Per column the W
// quarter is a wave-uniform sequential scalar stream (s_load_dwordx16
// batches) feeding v_fmac with per-lane h. Partials combined via ping-pong
// LDS; wave 0 keeps each lane's running (max,idx) -> one u64 key per (blk,b).
// No logits array, no shuffle reductions.
// ---------------------------------------------------------------------------
__global__ __launch_bounds__(256, 4) void k_projmax(
    const float* __restrict__ hT,     // [75][64][4]
    const float* __restrict__ outW,   // [V][300]
    const float* __restrict__ outb,   // [V]
    unsigned long long* __restrict__ bbuf)  // [NPB][64]
{
  const int w    = __builtin_amdgcn_readfirstlane(threadIdx.x >> 6);  // K-quarter
  const int lane = threadIdx.x & 63;                                  // batch row
  const int nc   = (w == 3) ? 18 : 19;      // float4 chunks in my quarter
  const int kbase = w * 19;                 // first chunk index

  // preload my h quarter into registers (coalesced float4 loads)
  float4 hreg[19];
#pragma unroll
  for (int c = 0; c < 19; c++) {
    const int cl = (c < nc) ? c : (nc - 1);
    hreg[c] = *(const float4*)(hT + (kbase + cl) * 256 + lane * 4);
  }
  if (nc == 18) hreg[18] = make_float4(0.f, 0.f, 0.f, 0.f);

  const int blk = blockIdx.x;
  const int c0 = (int)(((long long)blk * VD) >> 10);
  const int c1 = (int)(((long long)(blk + 1) * VD) >> 10);
  const int ngroups = (c1 - c0 + 15) >> 4;

  __shared__ float part[2][3][16][64];   // ping-pong x 3 partial waves

  float bestv = -INFINITY;
  int   besti = 0;

  for (int g = 0; g < ngroups; g++) {
    const int v0 = c0 + g * 16;
    float myacc[16];

#pragma unroll
    for (int cc = 0; cc < 16; cc++) {
      const int v = v0 + cc;
      const int vl = (v < VD) ? v : (VD - 1);
      const float* wrow = outW + (size_t)vl * HD + w * 76;   // wave-uniform
      float4 a = {0.f, 0.f, 0.f, 0.f};
#pragma unroll
      for (int c = 0; c < 19; c++) {
        const int cl = (c < nc) ? c : (nc - 1);
        const float4 wv = *(const float4*)(wrow + 4 * cl);   // s_load stream
        a.x += wv.x * hreg[c].x;
        a.y += wv.y * hreg[c].y;
        a.z += wv.z * hreg[c].z;
        a.w += wv.w * hreg[c].w;
      }
      myacc[cc] = (a.x + a.y) + (a.z + a.w);
    }

    if (w > 0) {
#pragma unroll
      for (int cc = 0; cc < 16; cc++)
        part[g & 1][w - 1][cc][lane] = myacc[cc];
    }
    __syncthreads();
    if (w == 0) {
#pragma unroll
      for (int cc = 0; cc < 16; cc++) {
        const int v = v0 + cc;
        const int vl = (v < VD) ? v : (VD - 1);
        const float tot = myacc[cc] + part[g & 1][0][cc][lane]
                        + part[g & 1][1][cc][lane] + part[g & 1][2][cc][lane]
                        + outb[vl];
        if (v < VD && tot > bestv) { bestv = tot; besti = v; }
      }
    }
  }

  if (w == 0) {
    unsigned u = __float_as_uint(bestv);
    u = (u & 0x80000000u) ? ~u : (u | 0x80000000u);
    const unsigned long long key =
        ((unsigned long long)u << 32) | (unsigned long long)(0xFFFFFFFFu - (unsigned)besti);
    bbuf[(size_t)blk * 64 + lane] = key;    // coalesced
  }
}

// ---------------------------------------------------------------------------
// k_fin: 64 blocks (one per batch row) x 320 threads. Reduce NPB keys ->
// token id; write out[s][b]; build next decoder x (transposed, relu).
// ---------------------------------------------------------------------------
__global__ __launch_bounds__(320) void k_fin(
    const unsigned long long* __restrict__ bbuf,
    const float* __restrict__ emb,
    float* __restrict__ out_row,     // out + s*B
    float* __restrict__ xdec)        // [75][64][4]
{
  const int b = blockIdx.x;

  unsigned long long best = 0ull;
  for (int i = threadIdx.x; i < NPB; i += 320)
    best = max(best, bbuf[(size_t)i * 64 + b]);

  const int lane = threadIdx.x & 63;
  const int wv = threadIdx.x >> 6;
#pragma unroll
  for (int off = 32; off >= 1; off >>= 1) {
    int lo = __shfl_xor((int)(unsigned)best, off, 64);
    int hi = __shfl_xor((int)(unsigned)(best >> 32), off, 64);
    unsigned long long o = ((unsigned long long)(unsigned)hi << 32) | (unsigned)lo;
    best = max(best, o);
  }

  __shared__ unsigned long long sm[5];
  __shared__ int sid;
  if (lane == 0) sm[wv] = best;
  __syncthreads();
  if (threadIdx.x == 0) {
    unsigned long long m = sm[0];
#pragma unroll
    for (int i = 1; i < 5; i++) m = max(m, sm[i]);
    const int id = (int)(0xFFFFFFFFu - (unsigned)(m & 0xFFFFFFFFull));
    out_row[b] = (float)id;
    sid = id;
  }
  __syncthreads();

  const int id = sid;
  const int k = threadIdx.x;
  if (k < HD) {
    xdec[tidx(k, b)] = fmaxf(emb[(size_t)id * HD + k], 0.f);
  }
}

// ---------------------------------------------------------------------------
extern "C" void kernel_launch(void* const* d_in, const int* in_sizes, int n_in,
                              void* d_out, int out_size, void* d_ws, size_t ws_size,
                              hipStream_t stream) {
  const int*   input  = (const int*)d_in[0];
  const float* emb    = (const float*)d_in[1];
  const float* eWih   = (const float*)d_in[2];
  const float* eWhh   = (const float*)d_in[3];
  const float* eBih   = (const float*)d_in[4];
  const float* eBhh   = (const float*)d_in[5];
  const float* dWih   = (const float*)d_in[6];
  const float* dWhh   = (const float*)d_in[7];
  const float* dBih   = (const float*)d_in[8];
  const float* dBhh   = (const float*)d_in[9];
  const float* outW   = (const float*)d_in[10];
  const float* outb   = (const float*)d_in[11];
  float* out = (float*)d_out;

  // ws layout: bbuf (u64, NPB*64) | hA | hB | xdec | xall
  unsigned long long* bbuf = (unsigned long long*)d_ws;
  float* fbase = (float*)((char*)d_ws + (size_t)NPB * 64 * 8);
  float* hA   = fbase;                 // 19200 floats
  float* hB   = fbase + 19200;
  float* xdec = fbase + 38400;
  float* xall = fbase + 57600;         // 64 * 19200 floats

  k_prep<<<dim3(LD, BD), 320, 0, stream>>>(input, emb, xall);
  k_init<<<BD, 320, 0, stream>>>(hA, emb, xdec);

  // ---- encoder ----
  for (int t = 0; t < LD; t++) {
    float* hin  = (t & 1) ? hB : hA;
    float* hout = (t & 1) ? hA : hB;
    k_gru<<<75, 384, 0, stream>>>(xall + t * (KC * 256), hin,
                                  eWih, eWhh, eBih, eBhh, hout);
  }
  // t=63 odd: enc_h in hA

  // ---- decoder ----
  for (int s = 0; s < LD; s++) {
    float* hin  = (s & 1) ? hB : hA;
    float* hout = (s & 1) ? hA : hB;
    k_gru<<<75, 384, 0, stream>>>(xdec, hin, dWih, dWhh, dBih, dBhh, hout);
    k_projmax<<<NPB, 256, 0, stream>>>(hout, outW, outb, bbuf);
    k_fin<<<BD, 320, 0, stream>>>(bbuf, emb, out + s * BD, xdec);
  }
}

// Round 5
// 6851.698 us; speedup vs baseline: 3.6194x; 1.5887x over previous
//
#include <hip/hip_runtime.h>

#define HD 300
#define KC 75
#define BD 64
#define VD 100000
#define LD 64
#define NM32 3126            // number of 32-row vocab groups (3126*32 = 100032)
#define NT16 6252            // number of 16-row vocab tiles
#define MARGIN 0.05f

typedef unsigned long long u64;
typedef short short8 __attribute__((ext_vector_type(8)));
typedef float f32x4 __attribute__((ext_vector_type(4)));

__device__ __forceinline__ float sigm(float x) { return 1.0f / (1.0f + expf(-x)); }

// Transposed k-chunked layout: T[kc][b][e] = X[b][4*kc+e].
__device__ __forceinline__ int tidx(int k, int b) {
  return (k >> 2) * 256 + b * 4 + (k & 3);
}

__device__ __forceinline__ unsigned enc32(float f) {
  unsigned u = __float_as_uint(f);
  return (u & 0x80000000u) ? ~u : (u | 0x80000000u);
}
__device__ __forceinline__ float dec32(unsigned e) {
  unsigned u = (e & 0x80000000u) ? (e & 0x7FFFFFFFu) : ~e;
  return __uint_as_float(u);
}
__device__ __forceinline__ unsigned short f2bf(float f) {   // RNE
  unsigned u = __float_as_uint(f);
  unsigned r = u + 0x7FFFu + ((u >> 16) & 1u);
  return (unsigned short)(r >> 16);
}
__device__ __forceinline__ u64 shfl64(u64 v, int m) {
  int lo = __shfl_xor((int)(unsigned)v, m, 64);
  int hi = __shfl_xor((int)(unsigned)(v >> 32), m, 64);
  return ((u64)(unsigned)hi << 32) | (unsigned)lo;
}
__device__ __forceinline__ void top2(u64 k, u64& b, u64& r) {
  if (k > b) { r = b; b = k; } else if (k > r) r = k;
}

// ---------------------------------------------------------------------------
// k_prep / k_init: unchanged from R3.
// ---------------------------------------------------------------------------
__global__ __launch_bounds__(320) void k_prep(
    const int* __restrict__ input, const float* __restrict__ emb,
    float* __restrict__ xall)
{
  const int t = blockIdx.x, b = blockIdx.y;
  const int k = threadIdx.x;
  if (k >= HD) return;
  const int id = input[t * BD + b];
  xall[t * (KC * 256) + tidx(k, b)] = emb[(size_t)id * HD + k];
}

__global__ __launch_bounds__(320) void k_init(
    float* __restrict__ hT, const float* __restrict__ emb, float* __restrict__ xdec)
{
  const int b = blockIdx.x;
  const int k = threadIdx.x;
  if (k >= HD) return;
  hT[tidx(k, b)] = 0.f;
  xdec[tidx(k, b)] = fmaxf(emb[k], 0.f);
}

// ---------------------------------------------------------------------------
// k_gru: unchanged from R3 (passed, fp32-exact).
// ---------------------------------------------------------------------------
__global__ __launch_bounds__(384) void k_gru(
    const float* __restrict__ xT, const float* __restrict__ hT_in,
    const float* __restrict__ W_ih, const float* __restrict__ W_hh,
    const float* __restrict__ b_ih, const float* __restrict__ b_hh,
    float* __restrict__ hT_out)
{
  const int w = __builtin_amdgcn_readfirstlane(threadIdx.x >> 6);
  const int b = threadIdx.x & 63;
  const int m = w & 1;
  const int g = w >> 1;
  const int i0 = blockIdx.x * 4;

  const float* src = m ? hT_in : xT;
  const float* M   = m ? W_hh : W_ih;
  const float* row0 = M + (size_t)(g * HD + i0) * HD;

  float4 a0 = {0,0,0,0}, a1 = {0,0,0,0}, a2 = {0,0,0,0}, a3 = {0,0,0,0};

  for (int kc = 0; kc < KC; kc++) {
    const float4 s = *(const float4*)(src + kc * 256 + b * 4);
    const float4 w0 = *(const float4*)(row0 + kc * 4);
    const float4 w1 = *(const float4*)(row0 + HD + kc * 4);
    const float4 w2 = *(const float4*)(row0 + 2 * HD + kc * 4);
    const float4 w3 = *(const float4*)(row0 + 3 * HD + kc * 4);
    a0.x += w0.x * s.x; a0.y += w0.y * s.y; a0.z += w0.z * s.z; a0.w += w0.w * s.w;
    a1.x += w1.x * s.x; a1.y += w1.y * s.y; a1.z += w1.z * s.z; a1.w += w1.w * s.w;
    a2.x += w2.x * s.x; a2.y += w2.y * s.y; a2.z += w2.z * s.z; a2.w += w2.w * s.w;
    a3.x += w3.x * s.x; a3.y += w3.y * s.y; a3.z += w3.z * s.z; a3.w += w3.w * s.w;
  }

  const float* bias = m ? b_hh : b_ih;
  __shared__ float sg[2][3][4][64];
  sg[m][g][0][b] = (a0.x + a0.y) + (a0.z + a0.w) + bias[g * HD + i0 + 0];
  sg[m][g][1][b] = (a1.x + a1.y) + (a1.z + a1.w) + bias[g * HD + i0 + 1];
  sg[m][g][2][b] = (a2.x + a2.y) + (a2.z + a2.w) + bias[g * HD + i0 + 2];
  sg[m][g][3][b] = (a3.x + a3.y) + (a3.z + a3.w) + bias[g * HD + i0 + 3];
  __syncthreads();

  if (w < 4) {
    const int r = w;
    const int i = i0 + r;
    const float rr = sigm(sg[0][0][r][b] + sg[1][0][r][b]);
    const float zz = sigm(sg[0][1][r][b] + sg[1][1][r][b]);
    const float nn = tanhf(sg[0][2][r][b] + rr * sg[1][2][r][b]);
    const float hp = hT_in[tidx(i, b)];
    hT_out[tidx(i, b)] = (1.f - zz) * nn + zz * hp;
  }
}

// ---------------------------------------------------------------------------
// k_pack: outW fp32 -> Wp bf16 in MFMA A-fragment order. Chunk (t16, kt) is
// 1 KB: [lane(64)][j(8)] with v = t16*16 + (lane&15), k = kt*32 + (lane>>4)*8 + j.
// Runs once per kernel_launch (ws re-poisoned each call).
// ---------------------------------------------------------------------------
__global__ __launch_bounds__(256) void k_pack(
    const float* __restrict__ outW, unsigned* __restrict__ Wp)
{
  const int t16 = blockIdx.x;
  const int d = threadIdx.x;          // 0..255: lane = d>>2, pair p = d&3
  const int lane = d >> 2, p = d & 3;
  const int v = t16 * 16 + (lane & 15);
  for (int kt = 0; kt < 10; kt++) {
    const int k = kt * 32 + (lane >> 4) * 8 + 2 * p;
    float f0 = 0.f, f1 = 0.f;
    if (v < VD) {
      if (k < HD)     f0 = outW[(size_t)v * HD + k];
      if (k + 1 < HD) f1 = outW[(size_t)v * HD + k + 1];
    }
    const unsigned out = (unsigned)f2bf(f0) | ((unsigned)f2bf(f1) << 16);
    Wp[((size_t)t16 * 10 + kt) * 256 + d] = out;
  }
}

// ---------------------------------------------------------------------------
// k_packh: h (fp32, transposed) -> hbp bf16 in MFMA B-fragment order.
// hbp[kt(10)][nt(4)][lane(64)][j(8)]: b = nt*16 + (lane&15), k = kt*32 + (lane>>4)*8 + j.
// ---------------------------------------------------------------------------
__global__ __launch_bounds__(256) void k_packh(
    const float* __restrict__ hT, unsigned* __restrict__ hbp)
{
  const int i = blockIdx.x * 256 + threadIdx.x;   // 0..10239 u32s
  if (i >= 10240) return;
  const int p = i & 3, lane = (i >> 2) & 63, nt = (i >> 8) & 3, kt = i >> 10;
  const int b = nt * 16 + (lane & 15);
  const int k = kt * 32 + (lane >> 4) * 8 + 2 * p;
  float f0 = (k < HD)     ? hT[tidx(k, b)]     : 0.f;
  float f1 = (k + 1 < HD) ? hT[tidx(k + 1, b)] : 0.f;
  hbp[i] = (unsigned)f2bf(f0) | ((unsigned)f2bf(f1) << 16);
}

// ---------------------------------------------------------------------------
// k_projbf: MFMA projection + per-32-row-group top-2 argmax keys.
// 782 blocks x 256 thr (4 waves). Wave wgid = m32 group (32 vocab rows):
// 2 M-tiles x 4 N-tiles of 16x16x32 bf16 MFMA over 10 K-steps. A from Wp
// (packed: coalesced dwordx4; else gathered fp32+cvt). B from hbp via LDS.
// Epilogue: per-lane top2 over 8 vals per b, butterfly-merge over 4 lanes,
// lane l writes b=l's (best, runner) keys for this group.
// ---------------------------------------------------------------------------
template <bool PACKED>
__global__ __launch_bounds__(256) void k_projbf(
    const unsigned* __restrict__ Wp, const float* __restrict__ outW,
    const unsigned* __restrict__ hbp, const float* __restrict__ outb,
    u64* __restrict__ bbuf)
{
  __shared__ unsigned hlds[10240];
  for (int i = threadIdx.x; i < 10240; i += 256) hlds[i] = hbp[i];
  __syncthreads();

  const int w = __builtin_amdgcn_readfirstlane(threadIdx.x >> 6);
  const int lane = threadIdx.x & 63;
  const int m32 = blockIdx.x * 4 + w;
  if (m32 >= NM32) return;
  const int m0 = m32 * 32;
  const int quad = lane >> 4;

  f32x4 acc[2][4];
#pragma unroll
  for (int mt = 0; mt < 2; mt++)
#pragma unroll
    for (int nt = 0; nt < 4; nt++) acc[mt][nt] = f32x4{0.f, 0.f, 0.f, 0.f};

  const int t0 = m32 * 2;

  for (int kt = 0; kt < 10; kt++) {
    short8 a[2];
    if (PACKED) {
#pragma unroll
      for (int mt = 0; mt < 2; mt++)
        a[mt] = *(const short8*)(Wp + ((size_t)(t0 + mt) * 10 + kt) * 256 + lane * 4);
    } else {
#pragma unroll
      for (int mt = 0; mt < 2; mt++) {
        const int v = (t0 + mt) * 16 + (lane & 15);
        const int kb = kt * 32 + quad * 8;
        const int vc = (v < VD) ? v : (VD - 1);
        short8 tmp;
#pragma unroll
        for (int e = 0; e < 8; e++) {
          const int kk = kb + e;
          const float f = (kk < HD && v < VD) ? outW[(size_t)vc * HD + kk] : 0.f;
          tmp[e] = (short)f2bf(f);
        }
        a[mt] = tmp;
      }
    }
#pragma unroll
    for (int nt = 0; nt < 4; nt++) {
      const short8 bf = *(const short8*)(&hlds[((kt * 4 + nt) << 8) + lane * 4]);
#pragma unroll
      for (int mt = 0; mt < 2; mt++)
        acc[mt][nt] = __builtin_amdgcn_mfma_f32_16x16x32_bf16(a[mt], bf, acc[mt][nt], 0, 0, 0);
    }
  }

  // ---- epilogue: top2 per batch column ----
  u64 best[4], run[4];
#pragma unroll
  for (int nt = 0; nt < 4; nt++) { best[nt] = 0ull; run[nt] = 0ull; }

#pragma unroll
  for (int mt = 0; mt < 2; mt++) {
    const int vb = m0 + mt * 16 + quad * 4;
    const int vbc = (vb <= VD - 4) ? vb : (VD - 4);
    const float4 ob = *(const float4*)(outb + vbc);
#pragma unroll
    for (int nt = 0; nt < 4; nt++) {
#pragma unroll
      for (int reg = 0; reg < 4; reg++) {
        const int v = vb + reg;
        if (v < VD) {
          const float obv = (reg == 0) ? ob.x : (reg == 1) ? ob.y : (reg == 2) ? ob.z : ob.w;
          const float val = acc[mt][nt][reg] + obv;
          const u64 key = ((u64)enc32(val) << 32) | (u64)(0xFFFFFFFFu - (unsigned)v);
          top2(key, best[nt], run[nt]);
        }
      }
    }
  }

#pragma unroll
  for (int nt = 0; nt < 4; nt++) {
    u64 ob = shfl64(best[nt], 16), orr = shfl64(run[nt], 16);
    top2(ob, best[nt], run[nt]); top2(orr, best[nt], run[nt]);
    ob = shfl64(best[nt], 32); orr = shfl64(run[nt], 32);
    top2(ob, best[nt], run[nt]); top2(orr, best[nt], run[nt]);
  }

  // lane l writes b = l  (nt = l>>4, col = l&15)
  u64 wb = best[0], wr = run[0];
  if (quad == 1) { wb = best[1]; wr = run[1]; }
  if (quad == 2) { wb = best[2]; wr = run[2]; }
  if (quad == 3) { wb = best[3]; wr = run[3]; }
  u64* dst = bbuf + (size_t)lane * (NM32 * 2) + (size_t)m32 * 2;
  dst[0] = wb; dst[1] = wr;
}

// ---------------------------------------------------------------------------
// k_fin2: per batch row: approx max over keys -> margin candidates -> exact
// fp32 rescore -> token + next decoder x.
// ---------------------------------------------------------------------------
__global__ __launch_bounds__(256) void k_fin2(
    const u64* __restrict__ bbuf, const float* __restrict__ hT,
    const float* __restrict__ outW, const float* __restrict__ outb,
    const float* __restrict__ emb,
    float* __restrict__ out_row, float* __restrict__ xdec)
{
  const int b = blockIdx.x;
  const int tid = threadIdx.x;
  const u64* keys = bbuf + (size_t)b * (NM32 * 2);

  __shared__ u64 red[256];
  u64 local = 0ull;
  for (int i = tid; i < NM32 * 2; i += 256) local = max(local, keys[i]);
  red[tid] = local;
  __syncthreads();
  for (int s2 = 128; s2 > 0; s2 >>= 1) {
    if (tid < s2) red[tid] = max(red[tid], red[tid + s2]);
    __syncthreads();
  }

  __shared__ unsigned s_te;
  __shared__ int s_n;
  if (tid == 0) {
    const float mv = dec32((unsigned)(red[0] >> 32));
    s_te = enc32(mv - MARGIN);
    s_n = 0;
  }
  __syncthreads();
  const unsigned te = s_te;

  __shared__ int cand[256];
  for (int i = tid; i < NM32 * 2; i += 256) {
    const u64 k = keys[i];
    if ((unsigned)(k >> 32) >= te && k != 0ull) {
      const int slot = atomicAdd(&s_n, 1);
      if (slot < 256) cand[slot] = (int)(0xFFFFFFFFu - (unsigned)k);
    }
  }
  __syncthreads();
  const int n = min(s_n, 256);

  u64 bk = 0ull;
  if (tid < n) {
    const int v = cand[tid];
    const float* wr = outW + (size_t)v * HD;
    float acc = 0.f;
    for (int k = 0; k < HD; k++) acc += wr[k] * hT[tidx(k, b)];
    acc += outb[v];
    bk = ((u64)enc32(acc) << 32) | (u64)(0xFFFFFFFFu - (unsigned)v);
  }
  red[tid] = bk;
  __syncthreads();
  for (int s2 = 128; s2 > 0; s2 >>= 1) {
    if (tid < s2) red[tid] = max(red[tid], red[tid + s2]);
    __syncthreads();
  }

  __shared__ int s_id;
  if (tid == 0) {
    const int id = (int)(0xFFFFFFFFu - (unsigned)(red[0] & 0xFFFFFFFFull));
    out_row[b] = (float)id;
    s_id = id;
  }
  __syncthreads();

  const int id = s_id;
  for (int k = tid; k < HD; k += 256)
    xdec[tidx(k, b)] = fmaxf(emb[(size_t)id * HD + k], 0.f);
}

// ---------------------------------------------------------------------------
extern "C" void kernel_launch(void* const* d_in, const int* in_sizes, int n_in,
                              void* d_out, int out_size, void* d_ws, size_t ws_size,
                              hipStream_t stream) {
  const int*   input  = (const int*)d_in[0];
  const float* emb    = (const float*)d_in[1];
  const float* eWih   = (const float*)d_in[2];
  const float* eWhh   = (const float*)d_in[3];
  const float* eBih   = (const float*)d_in[4];
  const float* eBhh   = (const float*)d_in[5];
  const float* dWih   = (const float*)d_in[6];
  const float* dWhh   = (const float*)d_in[7];
  const float* dBih   = (const float*)d_in[8];
  const float* dBhh   = (const float*)d_in[9];
  const float* outW   = (const float*)d_in[10];
  const float* outb   = (const float*)d_in[11];
  float* out = (float*)d_out;

  const size_t wpBytes = (size_t)NT16 * 10 * 1024;   // 64,020,480
  size_t need = wpBytes + 3201024 + 40960 + 5145600 + 6 * 256;
  const bool packed = ws_size >= need;

  size_t off = 0;
  auto take = [&](size_t nbytes) -> char* {
    char* p = (char*)d_ws + off;
    off += (nbytes + 255) & ~(size_t)255;
    return p;
  };

  unsigned* Wp = packed ? (unsigned*)take(wpBytes) : nullptr;
  u64*      bbuf = (u64*)take((size_t)BD * NM32 * 2 * 8);
  unsigned* hbp  = (unsigned*)take(40960);
  float* hA   = (float*)take(76800);
  float* hB   = (float*)take(76800);
  float* xdec = (float*)take(76800);
  float* xall = (float*)take((size_t)LD * 76800);

  if (packed) k_pack<<<NT16, 256, 0, stream>>>(outW, Wp);
  k_prep<<<dim3(LD, BD), 320, 0, stream>>>(input, emb, xall);
  k_init<<<BD, 320, 0, stream>>>(hA, emb, xdec);

  // ---- encoder ----
  for (int t = 0; t < LD; t++) {
    float* hin  = (t & 1) ? hB : hA;
    float* hout = (t & 1) ? hA : hB;
    k_gru<<<75, 384, 0, stream>>>(xall + t * (KC * 256), hin,
                                  eWih, eWhh, eBih, eBhh, hout);
  }
  // enc_h in hA

  // ---- decoder ----
  for (int s = 0; s < LD; s++) {
    float* hin  = (s & 1) ? hB : hA;
    float* hout = (s & 1) ? hA : hB;
    k_gru<<<75, 384, 0, stream>>>(xdec, hin, dWih, dWhh, dBih, dBhh, hout);
    k_packh<<<40, 256, 0, stream>>>(hout, hbp);
    if (packed)
      k_projbf<true><<<782, 256, 0, stream>>>(Wp, outW, hbp, outb, bbuf);
    else
      k_projbf<false><<<782, 256, 0, stream>>>(Wp, outW, hbp, outb, bbuf);
    k_fin2<<<BD, 256, 0, stream>>>(bbuf, hout, outW, outb, emb, out + s * BD, xdec);
  }
}